// Round 7
// baseline (48450.372 us; speedup 1.0000x reference)
//
#include <hip/hip_runtime.h>
#include <stdint.h>

// Exact replication of jax partitionable-threefry coverage sampling (verified
// R3..R6, absmax=0). R7: replace bitonic sorting networks (dependent shuffle
// chains) with rank passes using wave-uniform LDS broadcast reads:
//   P2b: per-wave rank of 64 thread-minima  -> sorted top-16 (wls)
//   P5:  rank of <=64 candidate u64 keys    -> direct top-16 emit
// Candidate buffer ping-pongs; next buffer pre-cleared to ~0 by wave 0.

namespace {

constexpr int BATCH = 8;
constexpr int NPTS  = 16384;
constexpr int NQ    = 4096;
constexpr int KNN   = 16;
constexpr int BLOCK = 512;            // 8 waves
constexpr int CH    = NPTS / BLOCK;   // 32 points per thread
constexpr int NWAVE = BLOCK / 64;     // 8
constexpr size_t IDX_ELEMS = (size_t)BATCH * NQ * KNN;  // 524288 f32, then pts

// swizzle: insert 1 u32 word of pad per 32 words (2 u16 per 64 u16)
__device__ __forceinline__ int swz32(int v) { return v + (v >> 5); }
__device__ __forceinline__ int swz16(int w) { return w + 2 * (w >> 6); }

// Threefry-2x32, 20 rounds, jax's exact schedule.
__device__ __forceinline__ void tf2x32(uint32_t k0, uint32_t k1,
                                       uint32_t x0, uint32_t x1,
                                       uint32_t &o0, uint32_t &o1) {
  uint32_t ks2 = k0 ^ k1 ^ 0x1BD11BDAu;
  x0 += k0; x1 += k1;
#define TFR(r) { x0 += x1; x1 = (x1 << (r)) | (x1 >> (32 - (r))); x1 ^= x0; }
  TFR(13) TFR(15) TFR(26) TFR(6)
  x0 += k1;  x1 += ks2 + 1u;
  TFR(17) TFR(29) TFR(16) TFR(24)
  x0 += ks2; x1 += k0 + 2u;
  TFR(13) TFR(15) TFR(26) TFR(6)
  x0 += k0;  x1 += k1 + 3u;
  TFR(17) TFR(29) TFR(16) TFR(24)
  x0 += k1;  x1 += ks2 + 4u;
  TFR(13) TFR(15) TFR(26) TFR(6)
  x0 += ks2; x1 += k0 + 5u;
#undef TFR
  o0 = x0; o1 = x1;
}

__device__ __forceinline__ void split_child(uint32_t pk0, uint32_t pk1,
                                            uint32_t i, uint32_t &c0, uint32_t &c1) {
  tf2x32(pk0, pk1, 0u, i, c0, c1);          // partitionable split
}

__device__ __forceinline__ uint32_t bits32_scalar(uint32_t k0, uint32_t k1) {
  uint32_t a0, a1;
  tf2x32(k0, k1, 0u, 0u, a0, a1);
  return a0 ^ a1;                            // partitionable 32-bit draw
}

__device__ __forceinline__ uint32_t jax_randint(uint32_t hi, uint32_t lo, uint32_t span) {
  uint32_t mult = 65536u % span;
  mult = (mult * mult) % span;               // 2^32 % span
  return ((hi % span) * mult + (lo % span)) % span;
}

__device__ __forceinline__ void ce_asc(float &a, float &b) {
  float lo = fminf(a, b), hi = fmaxf(a, b); a = lo; b = hi;
}

// bitonic clean of a 16-element bitonic sequence -> ascending (32 CE)
__device__ __forceinline__ void clean16(float e[16]) {
  #pragma unroll
  for (int j = 8; j > 0; j >>= 1) {
    #pragma unroll
    for (int i = 0; i < 16; ++i) {
      int l = i ^ j;
      if (l > i) ce_asc(e[i], e[l]);
    }
  }
}

// n-th (0-based) set bit of m, n < popcount(m)
__device__ __forceinline__ uint32_t nth_set_bit(uint32_t m, uint32_t n) {
  uint32_t pos = 0;
  #pragma unroll
  for (int sh = 16; sh > 0; sh >>= 1) {
    uint32_t c = __popc(m & ((1u << sh) - 1u));
    if (n >= c) { n -= c; m >>= sh; pos += sh; }
  }
  return pos;
}

struct U64x2 { unsigned long long x, y; };

} // namespace

__global__ __launch_bounds__(BLOCK, 2)
void snn_sample_kernel(const float* __restrict__ xyz, float* __restrict__ out) {
  const int b    = blockIdx.x;
  const int t    = threadIdx.x;
  const int wave = t >> 6;
  const int lane = t & 63;
  const float INF = __int_as_float(0x7f800000);

  __shared__ __align__(16) uint16_t used[16896];        // swizzled, 33792 B
  __shared__ uint32_t mask[BLOCK];      // bit j of word t: used[t*32+j]==cur
  __shared__ uint32_t waveSum[NWAVE];   // popcount per wave's 2048-pt chunk
  __shared__ uint32_t wvMin[NWAVE];     // rebuild scratch
  __shared__ __align__(16) float wmins[BLOCK];          // per-thread minima
  __shared__ __align__(16) float wls[NWAVE * 16];       // per-wave sorted 16
  __shared__ __align__(16) unsigned long long cnd[2][64];  // ping-pong
  __shared__ uint32_t rngHi[BLOCK];
  __shared__ uint32_t rngLo[BLOCK];
  __shared__ float    sPt[3];
  __shared__ uint32_t sNc, sCur;

  // ---- init --------------------------------------------------------------
  float px[CH], py[CH], pz[CH];
  {
    const float* sp = xyz + ((size_t)b * NPTS + (size_t)t * CH) * 3;
    #pragma unroll
    for (int j = 0; j < CH; ++j) {
      px[j] = sp[3 * j + 0];
      py[j] = sp[3 * j + 1];
      pz[j] = sp[3 * j + 2];
    }
  }
  {
    uint32_t* u32p = (uint32_t*)used;
    for (int i = t; i < 16896 / 2; i += BLOCK) u32p[i] = 0u;
  }
  mask[t] = 0xFFFFFFFFu;
  if (t < NWAVE) waveSum[t] = (uint32_t)(NPTS / NWAVE);   // 2048
  if (t < 64) { cnd[0][t] = ~0ull; cnd[1][t] = ~0ull; }
  if (t == 0) { sNc = 0u; sCur = 0u; }

  uint32_t kb0, kb1;
  split_child(0u, 42u, (uint32_t)b, kb0, kb1);   // batch key of split(key42,8)
  __syncthreads();

  for (int s = 0; s < NQ; ++s) {
    // ---- rng refill for steps [s, s+512) -----------------------------------
    if ((s & (BLOCK - 1)) == 0) {
      uint32_t ss = (uint32_t)(s + t);
      uint32_t ks0, ks1, u0, u1, v0, v1;
      split_child(kb0, kb1, ss, ks0, ks1);
      split_child(ks0, ks1, 0u, u0, u1);
      split_child(ks0, ks1, 1u, v0, v1);
      rngHi[t] = bits32_scalar(u0, u1);
      rngLo[t] = bits32_scalar(v0, v1);
      __syncthreads();
    }

    // ---- P1: span/r (redundant per thread), owner find ---------------------
    uint32_t ws[NWAVE];
    uint32_t span = 0;
    #pragma unroll
    for (int w = 0; w < NWAVE; ++w) { ws[w] = waveSum[w]; span += ws[w]; }
    uint32_t cur = sCur;

    if (span == 0u) {                    // rare rebuild: cur advanced
      uint32_t uvals[CH / 2];
      uint32_t mn = 0xFFFFFFFFu;
      const uint32_t* up32 = (const uint32_t*)used;
      #pragma unroll
      for (int j = 0; j < CH / 2; ++j) {
        uint32_t w2 = up32[swz32(t * (CH / 2) + j)];
        uvals[j] = w2;
        uint32_t a = w2 & 0xFFFFu, c = w2 >> 16;
        uint32_t m2 = a < c ? a : c;
        mn = m2 < mn ? m2 : mn;
      }
      #pragma unroll
      for (int m = 1; m < 64; m <<= 1) {
        uint32_t o = (uint32_t)__shfl_xor((int)mn, m, 64);
        mn = o < mn ? o : mn;
      }
      if (lane == 0) wvMin[wave] = mn;
      __syncthreads();
      uint32_t c = wvMin[0];
      #pragma unroll
      for (int w = 1; w < NWAVE; ++w) c = wvMin[w] < c ? wvMin[w] : c;
      cur = c;
      if (t == 0) sCur = c;
      uint32_t mw = 0;
      #pragma unroll
      for (int j = 0; j < CH / 2; ++j) {
        uint32_t w2 = uvals[j];
        if ((w2 & 0xFFFFu) == cur) mw |= 1u << (2 * j);
        if ((w2 >> 16)     == cur) mw |= 1u << (2 * j + 1);
      }
      mask[t] = mw;
      uint32_t pc = __popc(mw);
      #pragma unroll
      for (int m = 1; m < 64; m <<= 1) pc += (uint32_t)__shfl_xor((int)pc, m, 64);
      if (lane == 0) waveSum[wave] = pc;
      __syncthreads();
      span = 0;
      #pragma unroll
      for (int w = 0; w < NWAVE; ++w) { ws[w] = waveSum[w]; span += ws[w]; }
    }

    const uint32_t r = jax_randint(rngHi[s & (BLOCK - 1)],
                                   rngLo[s & (BLOCK - 1)], span);
    uint32_t preWave = 0;
    #pragma unroll
    for (int w = 0; w < NWAVE; ++w) preWave += (w < wave) ? ws[w] : 0u;
    if (r >= preWave && r < preWave + ws[wave]) {      // owner wave only
      uint32_t mw = mask[t];
      uint32_t pc = __popc(mw);
      uint32_t incl = pc;
      #pragma unroll
      for (int m = 1; m < 64; m <<= 1) {
        uint32_t v = (uint32_t)__shfl_up((int)incl, (unsigned)m, 64);
        if (lane >= m) incl += v;
      }
      uint32_t myBase = preWave + (incl - pc);
      if (r >= myBase && r < myBase + pc) {            // unique owner thread
        uint32_t pos = nth_set_bit(mw, r - myBase);
        uint32_t id = (uint32_t)t * CH + pos;
        const float* gp = xyz + ((size_t)b * NPTS + id) * 3;
        float fx = gp[0], fy = gp[1], fz = gp[2];
        sPt[0] = fx; sPt[1] = fy; sPt[2] = fz;
        float* po = out + IDX_ELEMS + ((size_t)b * NQ + s) * 3;
        po[0] = fx; po[1] = fy; po[2] = fz;
      }
    }
    __syncthreads();                                   // B2
    const float cx = sPt[0], cy = sPt[1], cz = sPt[2];

    // ---- P2: distances (strict RN, no FMA) + thread-min --------------------
    float dd[CH];
    float mymin = INF;
    #pragma unroll
    for (int j = 0; j < CH; ++j) {
      float dx = __fsub_rn(px[j], cx);
      float dy = __fsub_rn(py[j], cy);
      float dz = __fsub_rn(pz[j], cz);
      dd[j] = __fadd_rn(__fadd_rn(__fmul_rn(dx, dx), __fmul_rn(dy, dy)),
                        __fmul_rn(dz, dz));
      mymin = fminf(mymin, dd[j]);
    }

    // ---- P2b: in-wave rank of 64 minima -> wave's sorted top-16 ------------
    // (wave-synchronous LDS: write then uniform-address broadcast reads)
    wmins[t] = mymin;
    {
      uint32_t rank = 0;
      const float4* wp = (const float4*)&wmins[wave * 64];
      #pragma unroll
      for (int k = 0; k < 16; ++k) {
        float4 q = wp[k];                                // uniform addr -> bcast
        rank += (q.x < mymin || (q.x == mymin && (4 * k + 0) < lane)) ? 1u : 0u;
        rank += (q.y < mymin || (q.y == mymin && (4 * k + 1) < lane)) ? 1u : 0u;
        rank += (q.z < mymin || (q.z == mymin && (4 * k + 2) < lane)) ? 1u : 0u;
        rank += (q.w < mymin || (q.w == mymin && (4 * k + 3) < lane)) ? 1u : 0u;
      }
      if (rank < 16u) wls[wave * 16 + rank] = mymin;     // sorted by rank
    }
    __syncthreads();                                   // B3

    // ---- P3: every wave redundantly merges 8 sorted-16 lists -> U ----------
    float thr;
    {
      float M[16];
      if (lane < NWAVE) {
        #pragma unroll
        for (int i = 0; i < 16; ++i) M[i] = wls[lane * 16 + i];
      } else {
        #pragma unroll
        for (int i = 0; i < 16; ++i) M[i] = INF;
      }
      #pragma unroll
      for (int m = 1; m < NWAVE; m <<= 1) {
        float o[16];
        #pragma unroll
        for (int i = 0; i < 16; ++i) o[i] = __shfl_xor(M[i], m, 64);
        float T[16];
        #pragma unroll
        for (int i = 0; i < 16; ++i) T[i] = fminf(M[i], o[15 - i]);
        clean16(T);
        #pragma unroll
        for (int i = 0; i < 16; ++i) M[i] = T[i];
      }
      thr = __shfl(M[15], 0, 64);   // U >= true 16th-NN distance (exact bound)
    }

    // ---- P4: collect all (d,idx) with d <= U into ping buffer --------------
    {
      unsigned long long* cb = cnd[s & 1];
      #pragma unroll
      for (int j = 0; j < CH; ++j) {
        if (dd[j] <= thr) {
          uint32_t pos = atomicAdd(&sNc, 1u);
          if (pos < 64u) {
            cb[pos] = (((unsigned long long)__float_as_uint(dd[j])) << 32)
                      | (uint32_t)(t * CH + j);
          }
        }
      }
    }
    __syncthreads();                                   // B5

    // ---- P5: wave 0 ranks candidates (unique u64 keys), emits top-16 -------
    if (wave == 0) {
      const unsigned long long* cb = cnd[s & 1];
      unsigned long long v = cb[lane];                 // ~0 padding if unused
      uint32_t rank = 0;
      const U64x2* cp = (const U64x2*)cb;
      #pragma unroll
      for (int k = 0; k < 32; ++k) {
        U64x2 q = cp[k];                               // uniform addr -> bcast
        rank += (q.x < v) ? 1u : 0u;
        rank += (q.y < v) ? 1u : 0u;
      }
      if (lane == 0) sNc = 0u;
      cnd[(s & 1) ^ 1][lane] = ~0ull;                  // pre-clear next buffer
      if (rank < KNN) {                                // real keys: rank exact
        uint32_t id = (uint32_t)v;
        out[((size_t)b * NQ + s) * KNN + rank] = (float)id;   // exact in f32
        int a16 = swz16((int)id);
        uint32_t old = used[a16];
        used[a16] = (uint16_t)(old + 1u);              // +1 neighbors
        if (old == cur) {                              // leaves least-used set
          atomicAnd(&mask[id >> 5], ~(1u << (id & 31u)));
          atomicSub(&waveSum[id >> 11], 1u);
        }
        if (rank == 0u) {                              // center: +100 after +1
          uint32_t old2 = used[a16];
          used[a16] = (uint16_t)(old2 + 100u);
        }
      }
    }
    __syncthreads();                                   // B6 (loop top)
  }
}

extern "C" void kernel_launch(void* const* d_in, const int* in_sizes, int n_in,
                              void* d_out, int out_size, void* d_ws, size_t ws_size,
                              hipStream_t stream) {
  (void)in_sizes; (void)n_in; (void)d_ws; (void)ws_size; (void)out_size;
  const float* xyz = (const float*)d_in[0];
  float* out = (float*)d_out;
  snn_sample_kernel<<<dim3(BATCH), dim3(BLOCK), 0, stream>>>(xyz, out);
}

// Round 8
// 23143.684 us; speedup vs baseline: 2.0935x; 2.0935x over previous
//
#include <hip/hip_runtime.h>
#include <stdint.h>

// Exact replication of jax partitionable-threefry coverage sampling (verified
// R3..R6, absmax=0). R8 = R6 structure (best: 23.2 ms) with ONE change:
// __launch_bounds__(512, 1) instead of (512, 2).
// Rationale: only 8 blocks exist on 256 CUs (1 block/CU max regardless), so
// the ",2" bound only capped the allocator at 128 VGPRs — but px/py/pz+dd
// alone are 128 regs, forcing scratch spills (R6/R7 counters: paired extra
// FETCH+WRITE HBM traffic ≈ spill footprint; R7's extra temps made it 2x).
// 256-VGPR budget keeps all per-thread data register-resident.

namespace {

constexpr int BATCH = 8;
constexpr int NPTS  = 16384;
constexpr int NQ    = 4096;
constexpr int KNN   = 16;
constexpr int BLOCK = 512;            // 8 waves
constexpr int CH    = NPTS / BLOCK;   // 32 points per thread
constexpr int NWAVE = BLOCK / 64;     // 8
constexpr size_t IDX_ELEMS = (size_t)BATCH * NQ * KNN;  // 524288 f32, then pts

// swizzle: insert 1 u32 word of pad per 32 words (2 u16 per 64 u16)
__device__ __forceinline__ int swz32(int v) { return v + (v >> 5); }
__device__ __forceinline__ int swz16(int w) { return w + 2 * (w >> 6); }

// Threefry-2x32, 20 rounds, jax's exact schedule.
__device__ __forceinline__ void tf2x32(uint32_t k0, uint32_t k1,
                                       uint32_t x0, uint32_t x1,
                                       uint32_t &o0, uint32_t &o1) {
  uint32_t ks2 = k0 ^ k1 ^ 0x1BD11BDAu;
  x0 += k0; x1 += k1;
#define TFR(r) { x0 += x1; x1 = (x1 << (r)) | (x1 >> (32 - (r))); x1 ^= x0; }
  TFR(13) TFR(15) TFR(26) TFR(6)
  x0 += k1;  x1 += ks2 + 1u;
  TFR(17) TFR(29) TFR(16) TFR(24)
  x0 += ks2; x1 += k0 + 2u;
  TFR(13) TFR(15) TFR(26) TFR(6)
  x0 += k0;  x1 += k1 + 3u;
  TFR(17) TFR(29) TFR(16) TFR(24)
  x0 += k1;  x1 += ks2 + 4u;
  TFR(13) TFR(15) TFR(26) TFR(6)
  x0 += ks2; x1 += k0 + 5u;
#undef TFR
  o0 = x0; o1 = x1;
}

__device__ __forceinline__ void split_child(uint32_t pk0, uint32_t pk1,
                                            uint32_t i, uint32_t &c0, uint32_t &c1) {
  tf2x32(pk0, pk1, 0u, i, c0, c1);          // partitionable split
}

__device__ __forceinline__ uint32_t bits32_scalar(uint32_t k0, uint32_t k1) {
  uint32_t a0, a1;
  tf2x32(k0, k1, 0u, 0u, a0, a1);
  return a0 ^ a1;                            // partitionable 32-bit draw
}

__device__ __forceinline__ uint32_t jax_randint(uint32_t hi, uint32_t lo, uint32_t span) {
  uint32_t mult = 65536u % span;
  mult = (mult * mult) % span;               // 2^32 % span
  return ((hi % span) * mult + (lo % span)) % span;
}

__device__ __forceinline__ unsigned long long shflxor_u64(unsigned long long v, int m) {
  int lo = __shfl_xor((int)(uint32_t)v, m, 64);
  int hi = __shfl_xor((int)(uint32_t)(v >> 32), m, 64);
  return (((unsigned long long)(uint32_t)hi) << 32) | (uint32_t)lo;
}

__device__ __forceinline__ void ce_asc(float &a, float &b) {
  float lo = fminf(a, b), hi = fmaxf(a, b); a = lo; b = hi;
}

// bitonic clean of a 16-element bitonic sequence -> ascending (32 CE)
__device__ __forceinline__ void clean16(float e[16]) {
  #pragma unroll
  for (int j = 8; j > 0; j >>= 1) {
    #pragma unroll
    for (int i = 0; i < 16; ++i) {
      int l = i ^ j;
      if (l > i) ce_asc(e[i], e[l]);
    }
  }
}

// n-th (0-based) set bit of m, n < popcount(m)
__device__ __forceinline__ uint32_t nth_set_bit(uint32_t m, uint32_t n) {
  uint32_t pos = 0;
  #pragma unroll
  for (int sh = 16; sh > 0; sh >>= 1) {
    uint32_t c = __popc(m & ((1u << sh) - 1u));
    if (n >= c) { n -= c; m >>= sh; pos += sh; }
  }
  return pos;
}

} // namespace

__global__ __launch_bounds__(BLOCK, 1)
void snn_sample_kernel(const float* __restrict__ xyz, float* __restrict__ out) {
  const int b    = blockIdx.x;
  const int t    = threadIdx.x;
  const int wave = t >> 6;
  const int lane = t & 63;
  const float INF = __int_as_float(0x7f800000);

  __shared__ __align__(16) uint16_t used[16896];        // swizzled, 33792 B
  __shared__ uint32_t mask[BLOCK];      // bit j of word t: used[t*32+j]==cur
  __shared__ uint32_t waveSum[NWAVE];   // popcount per wave's 2048-pt chunk
  __shared__ uint32_t wvMin[NWAVE];     // rebuild scratch
  __shared__ float    wls[NWAVE * 16];  // per-wave sorted 16 smallest minima
  __shared__ unsigned long long cnd[64];
  __shared__ uint32_t rngHi[BLOCK];
  __shared__ uint32_t rngLo[BLOCK];
  __shared__ float    sPt[3];
  __shared__ uint32_t sNc, sCur;

  // ---- init --------------------------------------------------------------
  float px[CH], py[CH], pz[CH];
  {
    const float* sp = xyz + ((size_t)b * NPTS + (size_t)t * CH) * 3;
    #pragma unroll
    for (int j = 0; j < CH; ++j) {
      px[j] = sp[3 * j + 0];
      py[j] = sp[3 * j + 1];
      pz[j] = sp[3 * j + 2];
    }
  }
  {
    uint32_t* u32p = (uint32_t*)used;
    for (int i = t; i < 16896 / 2; i += BLOCK) u32p[i] = 0u;
  }
  mask[t] = 0xFFFFFFFFu;
  if (t < NWAVE) waveSum[t] = (uint32_t)(NPTS / NWAVE);   // 2048
  if (t == 0) { sNc = 0u; sCur = 0u; }

  uint32_t kb0, kb1;
  split_child(0u, 42u, (uint32_t)b, kb0, kb1);   // batch key of split(key42,8)
  __syncthreads();

  for (int s = 0; s < NQ; ++s) {
    // ---- rng refill for steps [s, s+512) -----------------------------------
    if ((s & (BLOCK - 1)) == 0) {
      uint32_t ss = (uint32_t)(s + t);
      uint32_t ks0, ks1, u0, u1, v0, v1;
      split_child(kb0, kb1, ss, ks0, ks1);
      split_child(ks0, ks1, 0u, u0, u1);
      split_child(ks0, ks1, 1u, v0, v1);
      rngHi[t] = bits32_scalar(u0, u1);
      rngLo[t] = bits32_scalar(v0, v1);
      __syncthreads();
    }

    // ---- P1: span/r (redundant per thread), owner find ---------------------
    uint32_t ws[NWAVE];
    uint32_t span = 0;
    #pragma unroll
    for (int w = 0; w < NWAVE; ++w) { ws[w] = waveSum[w]; span += ws[w]; }
    uint32_t cur = sCur;

    if (span == 0u) {                    // rare rebuild: cur advanced
      uint32_t uvals[CH / 2];
      uint32_t mn = 0xFFFFFFFFu;
      const uint32_t* up32 = (const uint32_t*)used;
      #pragma unroll
      for (int j = 0; j < CH / 2; ++j) {
        uint32_t w2 = up32[swz32(t * (CH / 2) + j)];
        uvals[j] = w2;
        uint32_t a = w2 & 0xFFFFu, c = w2 >> 16;
        uint32_t m2 = a < c ? a : c;
        mn = m2 < mn ? m2 : mn;
      }
      #pragma unroll
      for (int m = 1; m < 64; m <<= 1) {
        uint32_t o = (uint32_t)__shfl_xor((int)mn, m, 64);
        mn = o < mn ? o : mn;
      }
      if (lane == 0) wvMin[wave] = mn;
      __syncthreads();
      uint32_t c = wvMin[0];
      #pragma unroll
      for (int w = 1; w < NWAVE; ++w) c = wvMin[w] < c ? wvMin[w] : c;
      cur = c;
      if (t == 0) sCur = c;
      uint32_t mw = 0;
      #pragma unroll
      for (int j = 0; j < CH / 2; ++j) {
        uint32_t w2 = uvals[j];
        if ((w2 & 0xFFFFu) == cur) mw |= 1u << (2 * j);
        if ((w2 >> 16)     == cur) mw |= 1u << (2 * j + 1);
      }
      mask[t] = mw;
      uint32_t pc = __popc(mw);
      #pragma unroll
      for (int m = 1; m < 64; m <<= 1) pc += (uint32_t)__shfl_xor((int)pc, m, 64);
      if (lane == 0) waveSum[wave] = pc;
      __syncthreads();
      span = 0;
      #pragma unroll
      for (int w = 0; w < NWAVE; ++w) { ws[w] = waveSum[w]; span += ws[w]; }
    }

    const uint32_t r = jax_randint(rngHi[s & (BLOCK - 1)],
                                   rngLo[s & (BLOCK - 1)], span);
    uint32_t preWave = 0;
    #pragma unroll
    for (int w = 0; w < NWAVE; ++w) preWave += (w < wave) ? ws[w] : 0u;
    if (r >= preWave && r < preWave + ws[wave]) {      // owner wave only
      uint32_t mw = mask[t];
      uint32_t pc = __popc(mw);
      uint32_t incl = pc;
      #pragma unroll
      for (int m = 1; m < 64; m <<= 1) {
        uint32_t v = (uint32_t)__shfl_up((int)incl, (unsigned)m, 64);
        if (lane >= m) incl += v;
      }
      uint32_t myBase = preWave + (incl - pc);
      if (r >= myBase && r < myBase + pc) {            // unique owner thread
        uint32_t pos = nth_set_bit(mw, r - myBase);
        uint32_t id = (uint32_t)t * CH + pos;
        const float* gp = xyz + ((size_t)b * NPTS + id) * 3;
        float fx = gp[0], fy = gp[1], fz = gp[2];
        sPt[0] = fx; sPt[1] = fy; sPt[2] = fz;
        float* po = out + IDX_ELEMS + ((size_t)b * NQ + s) * 3;
        po[0] = fx; po[1] = fy; po[2] = fz;
      }
    }
    __syncthreads();                                   // B2
    const float cx = sPt[0], cy = sPt[1], cz = sPt[2];

    // ---- P2: distances (strict RN, no FMA) + thread-min + wave sort-64 -----
    float dd[CH];
    float mymin = INF;
    #pragma unroll
    for (int j = 0; j < CH; ++j) {
      float dx = __fsub_rn(px[j], cx);
      float dy = __fsub_rn(py[j], cy);
      float dz = __fsub_rn(pz[j], cz);
      dd[j] = __fadd_rn(__fadd_rn(__fmul_rn(dx, dx), __fmul_rn(dy, dy)),
                        __fmul_rn(dz, dz));
      mymin = fminf(mymin, dd[j]);
    }
    {
      float v = mymin;
      #pragma unroll
      for (int k = 2; k <= 64; k <<= 1) {
        #pragma unroll
        for (int j = k >> 1; j > 0; j >>= 1) {
          float o = __shfl_xor(v, j, 64);
          bool up = ((lane & k) == 0);
          bool keepmin = (((lane & j) == 0) == up);
          float mn = fminf(v, o), mx = fmaxf(v, o);
          v = keepmin ? mn : mx;
        }
      }
      if (lane < 16) wls[wave * 16 + lane] = v;
    }
    __syncthreads();                                   // B3

    // ---- P3: every wave redundantly merges 8 lists -> U (no extra barrier) -
    float thr;
    {
      float M[16];
      if (lane < NWAVE) {
        #pragma unroll
        for (int i = 0; i < 16; ++i) M[i] = wls[lane * 16 + i];
      } else {
        #pragma unroll
        for (int i = 0; i < 16; ++i) M[i] = INF;
      }
      #pragma unroll
      for (int m = 1; m < NWAVE; m <<= 1) {
        float o[16];
        #pragma unroll
        for (int i = 0; i < 16; ++i) o[i] = __shfl_xor(M[i], m, 64);
        float T[16];
        #pragma unroll
        for (int i = 0; i < 16; ++i) T[i] = fminf(M[i], o[15 - i]);
        clean16(T);
        #pragma unroll
        for (int i = 0; i < 16; ++i) M[i] = T[i];
      }
      thr = __shfl(M[15], 0, 64);   // U >= true 16th-NN distance (exact bound)
    }

    // ---- P4: collect all (d,idx) with d <= U (superset of true top-16) -----
    #pragma unroll
    for (int j = 0; j < CH; ++j) {
      if (dd[j] <= thr) {
        uint32_t pos = atomicAdd(&sNc, 1u);
        if (pos < 64u) {
          cnd[pos] = (((unsigned long long)__float_as_uint(dd[j])) << 32)
                     | (uint32_t)(t * CH + j);
        }
      }
    }
    __syncthreads();                                   // B5

    // ---- P5: wave 0 sorts candidates, emits top-16, updates state ----------
    if (wave == 0) {
      uint32_t nc = sNc; if (nc > 64u) nc = 64u;
      unsigned long long v = (lane < (int)nc) ? cnd[lane] : ~0ull;
      if (lane == 17) sNc = 0u;       // reset after loads (in-wave order)
      #pragma unroll
      for (int k = 2; k <= 32; k <<= 1) {
        #pragma unroll
        for (int j = k >> 1; j > 0; j >>= 1) {
          unsigned long long o = shflxor_u64(v, j);
          bool up = ((lane & k) == 0);
          bool keepmin = (((lane & j) == 0) == up);
          unsigned long long mn = (v < o) ? v : o;
          unsigned long long mx = (v < o) ? o : v;
          v = keepmin ? mn : mx;
        }
      }
      if (nc > 32u) {                 // finish full sort-64 only if needed
        #pragma unroll
        for (int j = 32; j > 0; j >>= 1) {
          unsigned long long o = shflxor_u64(v, j);
          bool keepmin = ((lane & j) == 0);
          unsigned long long mn = (v < o) ? v : o;
          unsigned long long mx = (v < o) ? o : v;
          v = keepmin ? mn : mx;
        }
      }
      // lane i holds rank-i (d,idx); ranks 0..15 are the stable top-16
      if (lane < KNN) {
        uint32_t id = (uint32_t)v;
        out[((size_t)b * NQ + s) * KNN + lane] = (float)id;   // exact in f32
        int a16 = swz16((int)id);
        uint32_t old = used[a16];
        used[a16] = (uint16_t)(old + 1u);                     // +1 neighbors
        if (old == cur) {                                     // leaves the set
          atomicAnd(&mask[id >> 5], ~(1u << (id & 31u)));
          atomicSub(&waveSum[id >> 11], 1u);
        }
      }
      if (lane == 0) {                                        // rank 0 == center
        uint32_t cidx = (uint32_t)v;
        int a16 = swz16((int)cidx);
        uint32_t old = used[a16];                             // sees own +1
        used[a16] = (uint16_t)(old + 100u);                   // +100 center
      }
    }
    __syncthreads();                                   // B6 (loop top)
  }
}

extern "C" void kernel_launch(void* const* d_in, const int* in_sizes, int n_in,
                              void* d_out, int out_size, void* d_ws, size_t ws_size,
                              hipStream_t stream) {
  (void)in_sizes; (void)n_in; (void)d_ws; (void)ws_size; (void)out_size;
  const float* xyz = (const float*)d_in[0];
  float* out = (float*)d_out;
  snn_sample_kernel<<<dim3(BATCH), dim3(BLOCK), 0, stream>>>(xyz, out);
}